// Round 1
// baseline (571.096 us; speedup 1.0000x reference)
//
#include <hip/hip_runtime.h>
#include <cstdint>
#include <cstddef>

// Problem constants (DAC RVQ VAE bottleneck)
constexpr int T   = 4096;
constexpr int BB  = 16;
constexpr int D   = 128;   // INPUT_DIM
constexpr int CB  = 1024;  // CODEBOOK_SIZE
constexpr int CD  = 8;     // CODEBOOK_DIM
constexpr int NCB = 9;     // N_CODEBOOKS

constexpr int TBLK = 64;   // columns (t positions) per block
constexpr int NTHR = 256;  // 4 waves

// Output layout (flat f32 concat, reference return order):
//   z_q [16*128*4096] | kl [1] | commit [1] | cbloss [1] | codes [16*9*4096] | latents [16*72*4096]
constexpr size_t OFF_ZQ    = 0;
constexpr size_t OFF_SCAL  = (size_t)BB * D * T;            // 8388608
constexpr size_t OFF_CODES = OFF_SCAL + 3;                  // 8388611
constexpr size_t OFF_LAT   = OFF_CODES + (size_t)BB * NCB * T; // 8978435

// ---------------------------------------------------------------------------
// Prep: normalize codebook rows (cb / max(||cb||,1e-12)), store 0.5*||cbn||^2,
// and zero the three scalar accumulator slots in d_out.
// ---------------------------------------------------------------------------
__global__ void prep_kernel(const float* __restrict__ codebook,
                            float* __restrict__ cbn,
                            float* __restrict__ h2,
                            float* __restrict__ scal) {
    int e = blockIdx.x * blockDim.x + threadIdx.x;
    if (e == 0) { scal[0] = 0.f; scal[1] = 0.f; scal[2] = 0.f; }
    if (e < NCB * CB) {
        float v[CD];
        float s2 = 0.f;
#pragma unroll
        for (int j = 0; j < CD; ++j) { v[j] = codebook[e * CD + j]; s2 = fmaf(v[j], v[j], s2); }
        float inv = 1.0f / fmaxf(sqrtf(s2), 1e-12f);
        float c2 = 0.f;
#pragma unroll
        for (int j = 0; j < CD; ++j) { float t = v[j] * inv; cbn[e * CD + j] = t; c2 = fmaf(t, t, c2); }
        h2[e] = 0.5f * c2;
    }
}

// ---------------------------------------------------------------------------
// Main fused kernel: one block = 64 consecutive t positions of one batch b.
// ---------------------------------------------------------------------------
__global__ __launch_bounds__(NTHR, 4)
void rvq_kernel(const float* __restrict__ x,
                const float* __restrict__ noise,
                const float* __restrict__ in_w,
                const float* __restrict__ in_b,
                const float* __restrict__ codebook,
                const float* __restrict__ out_w,
                const float* __restrict__ out_b,
                const float* __restrict__ cbn,
                const float* __restrict__ h2,
                float* __restrict__ o_zq,
                float* __restrict__ o_scal,
                float* __restrict__ o_codes,
                float* __restrict__ o_lat) {
    __shared__ float res[D * TBLK];      // res[k][c], k=0..127, c=0..63 (32 KB)
    __shared__ float ze[CD * TBLK];      // z_e tile [j][c] (2 KB)
    __shared__ float scbuf[4 * TBLK];    // per-wave best score
    __shared__ int   sibuf[4 * TBLK];    // per-wave best index
    __shared__ float redw[8];

    const int tid = threadIdx.x;
    const int c   = tid & 63;            // column within tile
    const int s   = tid >> 6;            // wave id (uniform per wave)
    const int su  = __builtin_amdgcn_readfirstlane(s); // provably wave-uniform
    const int b   = blockIdx.x >> 6;
    const int t0  = (blockIdx.x & 63) << 6;
    const int t   = t0 + c;

    // ---------------- phase 0: vae_sample -> z into res, local KL ----------
    float kl_local = 0.f;
    {
        const float* xm = x     + (size_t)b * 2 * D * T + (size_t)(su * 32) * T + t;
        const float* xs = xm    + (size_t)D * T;
        const float* nz = noise + (size_t)b * D * T     + (size_t)(su * 32) * T + t;
#pragma unroll 8
        for (int k = 0; k < 32; ++k) {
            float m  = xm[(size_t)k * T];
            float sc = xs[(size_t)k * T];
            float nv = nz[(size_t)k * T];
            float sp  = fmaxf(sc, 0.f) + log1pf(expf(-fabsf(sc)));  // softplus
            float sd  = sp + 1e-4f;
            float var = sd * sd;
            float zv  = fmaf(nv, sd, m);
            res[(su * 32 + k) * TBLK + c] = zv;
            kl_local += m * m + var - logf(var) - 1.0f;
        }
    }

    float loss_local = 0.f;

    // ---------------- RVQ loop over 9 codebooks ----------------------------
    for (int i = 0; i < NCB; ++i) {
        __syncthreads();  // res tile finalized (phase 0 or previous update)

        // in_proj: this wave computes z_e rows d = su and su+4 for all 64 cols
        {
            const float* w0 = in_w + (size_t)(i * CD + su) * D;       // uniform
            const float* w1 = w0 + 4 * D;
            float a0 = in_b[i * CD + su];
            float a1 = in_b[i * CD + su + 4];
#pragma unroll 16
            for (int k = 0; k < D; ++k) {
                float r = res[k * TBLK + c];
                a0 = fmaf(w0[k], r, a0);
                a1 = fmaf(w1[k], r, a1);
            }
            ze[su * TBLK + c]       = a0;
            ze[(su + 4) * TBLK + c] = a1;
            // latents output (raw z_e)
            o_lat[(size_t)b * (NCB * CD) * T + (size_t)(i * CD + su) * T + t]     = a0;
            o_lat[(size_t)b * (NCB * CD) * T + (size_t)(i * CD + su + 4) * T + t] = a1;
        }
        __syncthreads();

        // load raw z_e of my column, L2-normalize (as reference does)
        float zer[CD], en[CD];
        float n2 = 0.f;
#pragma unroll
        for (int j = 0; j < CD; ++j) { zer[j] = ze[j * TBLK + c]; n2 = fmaf(zer[j], zer[j], n2); }
        float inv = 1.0f / fmaxf(sqrtf(n2), 1e-12f);
#pragma unroll
        for (int j = 0; j < CD; ++j) en[j] = zer[j] * inv;

        // search: wave su scans entries [su*256, su*256+256), uniform addrs -> SMEM
        float best = -3.0e38f;
        int   bloc = 0;
        {
            const float* cb = cbn + ((size_t)i * CB + su * 256) * CD;  // uniform
            const float* hh = h2  + i * CB + su * 256;                  // uniform
#pragma unroll 4
            for (int jj = 0; jj < 256; ++jj) {
                float sc0 = -hh[jj];                       // score = dot - 0.5*||cbn||^2
#pragma unroll
                for (int k = 0; k < CD; ++k) sc0 = fmaf(cb[jj * CD + k], en[k], sc0);
                if (sc0 > best) { best = sc0; bloc = jj; } // strict > : first-index tie-break
            }
        }
        scbuf[s * TBLK + c] = best;
        sibuf[s * TBLK + c] = su * 256 + bloc;
        __syncthreads();

        // reduce 4 candidates (ascending range order preserves argmin tie-break)
        float bsc = scbuf[c];
        int   bi  = sibuf[c];
#pragma unroll
        for (int ss = 1; ss < 4; ++ss) {
            float v2 = scbuf[ss * TBLK + c];
            int   vi = sibuf[ss * TBLK + c];
            if (v2 > bsc) { bsc = v2; bi = vi; }
        }
        if (s == 0) o_codes[(size_t)b * NCB * T + (size_t)i * T + t] = (float)bi;

        // straight-through zq = z_e + (cb_raw[idx] - z_e); loss (once per column)
        float zq[CD];
        {
            const float4* cr4 = (const float4*)(codebook + ((size_t)i * CB + bi) * CD);
            float4 qa = cr4[0], qb = cr4[1];
            float cv[CD] = {qa.x, qa.y, qa.z, qa.w, qb.x, qb.y, qb.z, qb.w};
#pragma unroll
            for (int j = 0; j < CD; ++j) {
                zq[j] = zer[j] + (cv[j] - zer[j]);
                if (s == 0) { float dd = cv[j] - zer[j]; loss_local = fmaf(dd, dd, loss_local); }
            }
        }

        // out_proj + residual update: this wave owns d in [su*32, su*32+32)
        {
            const float* ow = out_w + (size_t)(i * D + su * 32) * CD;  // uniform
            const float* ob = out_b + i * D + su * 32;                 // uniform
#pragma unroll 4
            for (int k = 0; k < 32; ++k) {
                float acc = ob[k];
#pragma unroll
                for (int j = 0; j < CD; ++j) acc = fmaf(ow[k * CD + j], zq[j], acc);
                res[(su * 32 + k) * TBLK + c] -= acc;   // unique owner per (d,c)
            }
        }
    }
    __syncthreads();

    // ---------------- final: z_q = z - residual (recompute z) --------------
    {
        const float* xm = x     + (size_t)b * 2 * D * T + (size_t)(su * 32) * T + t;
        const float* xs = xm    + (size_t)D * T;
        const float* nz = noise + (size_t)b * D * T     + (size_t)(su * 32) * T + t;
        float*       oq = o_zq  + (size_t)b * D * T     + (size_t)(su * 32) * T + t;
#pragma unroll 8
        for (int k = 0; k < 32; ++k) {
            float m  = xm[(size_t)k * T];
            float sc = xs[(size_t)k * T];
            float nv = nz[(size_t)k * T];
            float sp = fmaxf(sc, 0.f) + log1pf(expf(-fabsf(sc)));
            float sd = sp + 1e-4f;
            float zv = fmaf(nv, sd, m);
            oq[(size_t)k * T] = zv - res[(su * 32 + k) * TBLK + c];
        }
    }

    // ---------------- scalar reductions ------------------------------------
    float v = kl_local;
#pragma unroll
    for (int o = 32; o > 0; o >>= 1) v += __shfl_down(v, o, 64);
    float w2 = loss_local;
#pragma unroll
    for (int o = 32; o > 0; o >>= 1) w2 += __shfl_down(w2, o, 64);
    if ((tid & 63) == 0) { redw[s] = v; redw[4 + s] = w2; }
    __syncthreads();
    if (tid == 0) {
        float ks = redw[0] + redw[1] + redw[2] + redw[3];
        float ls = redw[4] + redw[5] + redw[6] + redw[7];
        atomicAdd(&o_scal[0], ks * (1.0f / 65536.0f));               // kl: /(B*T)
        float lsn = ls * (1.0f / (524288.0f * 9.0f));                // /(B*8*T)/NCB
        atomicAdd(&o_scal[1], lsn);                                  // commitment
        atomicAdd(&o_scal[2], lsn);                                  // codebook (identical in eval)
    }
}

extern "C" void kernel_launch(void* const* d_in, const int* in_sizes, int n_in,
                              void* d_out, int out_size, void* d_ws, size_t ws_size,
                              hipStream_t stream) {
    const float* x        = (const float*)d_in[0];
    const float* noise    = (const float*)d_in[1];
    const float* in_w     = (const float*)d_in[2];
    const float* in_b     = (const float*)d_in[3];
    const float* codebook = (const float*)d_in[4];
    const float* out_w    = (const float*)d_in[5];
    const float* out_b    = (const float*)d_in[6];

    float* out     = (float*)d_out;
    float* o_zq    = out + OFF_ZQ;
    float* o_scal  = out + OFF_SCAL;
    float* o_codes = out + OFF_CODES;
    float* o_lat   = out + OFF_LAT;

    // workspace: normalized codebook + half squared norms
    float* cbn = (float*)d_ws;                 // 9*1024*8 floats
    float* h2  = cbn + (size_t)NCB * CB * CD;  // 9*1024 floats

    prep_kernel<<<(NCB * CB + 255) / 256, 256, 0, stream>>>(codebook, cbn, h2, o_scal);

    dim3 grid(BB * (T / TBLK));  // 16 * 64 = 1024 blocks
    rvq_kernel<<<grid, NTHR, 0, stream>>>(x, noise, in_w, in_b, codebook, out_w, out_b,
                                          cbn, h2, o_zq, o_scal, o_codes, o_lat);
}

// Round 2
// 452.016 us; speedup vs baseline: 1.2634x; 1.2634x over previous
//
#include <hip/hip_runtime.h>
#include <cstdint>
#include <cstddef>

// Problem constants (DAC RVQ VAE bottleneck)
constexpr int T   = 4096;
constexpr int BB  = 16;
constexpr int D   = 128;   // INPUT_DIM
constexpr int CB  = 1024;  // CODEBOOK_SIZE
constexpr int CD  = 8;     // CODEBOOK_DIM
constexpr int NCB = 9;     // N_CODEBOOKS

constexpr int TBLK = 64;   // columns (t positions) per block
constexpr int NTHR = 256;  // 4 waves

// Output layout (flat f32 concat, reference return order):
//   z_q [16*128*4096] | kl [1] | commit [1] | cbloss [1] | codes [16*9*4096] | latents [16*72*4096]
constexpr size_t OFF_ZQ    = 0;
constexpr size_t OFF_SCAL  = (size_t)BB * D * T;               // 8388608
constexpr size_t OFF_CODES = OFF_SCAL + 3;                     // 8388611
constexpr size_t OFF_LAT   = OFF_CODES + (size_t)BB * NCB * T; // 8978435

// ---------------------------------------------------------------------------
// Prep: normalize codebook rows (cb / max(||cb||,1e-12)), store 0.5*||cbn||^2,
// and zero the three scalar accumulator slots in d_out.
// ---------------------------------------------------------------------------
__global__ void prep_kernel(const float* __restrict__ codebook,
                            float* __restrict__ cbn,
                            float* __restrict__ h2,
                            float* __restrict__ scal) {
    int e = blockIdx.x * blockDim.x + threadIdx.x;
    if (e == 0) { scal[0] = 0.f; scal[1] = 0.f; scal[2] = 0.f; }
    if (e < NCB * CB) {
        float v[CD];
        float s2 = 0.f;
#pragma unroll
        for (int j = 0; j < CD; ++j) { v[j] = codebook[e * CD + j]; s2 = fmaf(v[j], v[j], s2); }
        float inv = 1.0f / fmaxf(sqrtf(s2), 1e-12f);
        float c2 = 0.f;
#pragma unroll
        for (int j = 0; j < CD; ++j) { float t = v[j] * inv; cbn[e * CD + j] = t; c2 = fmaf(t, t, c2); }
        h2[e] = 0.5f * c2;
    }
}

// ---------------------------------------------------------------------------
// Main fused kernel: one block = 64 consecutive t positions of one batch b.
// Search is register-blocked: each thread owns 4 columns x one 64-entry chunk.
// ---------------------------------------------------------------------------
__global__ __launch_bounds__(NTHR, 4)
void rvq_kernel(const float* __restrict__ x,
                const float* __restrict__ noise,
                const float* __restrict__ in_w,
                const float* __restrict__ in_b,
                const float* __restrict__ codebook,
                const float* __restrict__ out_w,
                const float* __restrict__ out_b,
                const float* __restrict__ cbn,
                const float* __restrict__ h2,
                float* __restrict__ o_zq,
                float* __restrict__ o_scal,
                float* __restrict__ o_codes,
                float* __restrict__ o_lat) {
    __shared__ float res[D * TBLK];        // res[k][c], 32 KB
    __shared__ float zen[TBLK * 9];        // raw z_e, col-major stride 9 (2.25 KB)
    __shared__ float redS[4 * TBLK];       // per-wave best score (1 KB)
    __shared__ int   redI[4 * TBLK];       // per-wave best index (1 KB)
    __shared__ float redw[8];

    const int tid = threadIdx.x;
    const int c   = tid & 63;            // column for col-parallel phases
    const int s   = tid >> 6;            // wave id
    const int su  = __builtin_amdgcn_readfirstlane(s);
    const int b   = blockIdx.x >> 6;
    const int t0  = (blockIdx.x & 63) << 6;
    const int t   = t0 + c;

    // search-phase mapping
    const int l     = tid & 63;
    const int g     = l & 15;            // col-quad: cols 4g..4g+3
    const int chunk = su * 4 + (l >> 4); // entry chunk: [chunk*64, chunk*64+64)

    // ---------------- phase 0: vae_sample -> z into res, local KL ----------
    float kl_local = 0.f;
    {
        const float* xm = x     + (size_t)b * 2 * D * T + (size_t)(su * 32) * T + t;
        const float* xs = xm    + (size_t)D * T;
        const float* nz = noise + (size_t)b * D * T     + (size_t)(su * 32) * T + t;
#pragma unroll 8
        for (int k = 0; k < 32; ++k) {
            float m  = xm[(size_t)k * T];
            float sc = xs[(size_t)k * T];
            float nv = nz[(size_t)k * T];
            float sp  = fmaxf(sc, 0.f) + log1pf(expf(-fabsf(sc)));  // softplus
            float sd  = sp + 1e-4f;
            float var = sd * sd;
            float zv  = fmaf(nv, sd, m);
            res[(su * 32 + k) * TBLK + c] = zv;
            kl_local += m * m + var - logf(var) - 1.0f;
        }
    }

    float loss_local = 0.f;

    // ---------------- RVQ loop over 9 codebooks ----------------------------
    for (int i = 0; i < NCB; ++i) {
        __syncthreads();  // res + zen free for reuse

        // in_proj: wave computes z_e rows d = su, su+4 for all 64 cols
        {
            const float* w0 = in_w + (size_t)(i * CD + su) * D;   // uniform
            const float* w1 = w0 + 4 * D;
            float a0 = in_b[i * CD + su];
            float a1 = in_b[i * CD + su + 4];
#pragma unroll 16
            for (int k = 0; k < D; ++k) {
                float r = res[k * TBLK + c];
                a0 = fmaf(w0[k], r, a0);
                a1 = fmaf(w1[k], r, a1);
            }
            zen[c * 9 + su]     = a0;
            zen[c * 9 + su + 4] = a1;
            o_lat[(size_t)b * (NCB * CD) * T + (size_t)(i * CD + su) * T + t]     = a0;
            o_lat[(size_t)b * (NCB * CD) * T + (size_t)(i * CD + su + 4) * T + t] = a1;
        }
        __syncthreads();

        // ---- search: 4 cols/thread, 64-entry chunk/thread, L1-hit loads ---
        float en4[4][CD];
#pragma unroll
        for (int q = 0; q < 4; ++q) {
            const int cc = 4 * g + q;
            float v[CD];
            float n2 = 0.f;
#pragma unroll
            for (int j = 0; j < CD; ++j) { v[j] = zen[cc * 9 + j]; n2 = fmaf(v[j], v[j], n2); }
            float inv = 1.0f / fmaxf(sqrtf(n2), 1e-12f);
#pragma unroll
            for (int j = 0; j < CD; ++j) en4[q][j] = v[j] * inv;
        }

        float best[4] = {-3.0e38f, -3.0e38f, -3.0e38f, -3.0e38f};
        int   bidx[4] = {0, 0, 0, 0};
        {
            const float* cbb = cbn + ((size_t)i * CB + chunk * 64) * CD;
            const float* hb  = h2  + i * CB + chunk * 64;
#pragma unroll 4
            for (int jj = 0; jj < 64; ++jj) {
                const float4* r4 = (const float4*)(cbb + jj * CD);
                float4 ca = r4[0], cb4 = r4[1];
                float hv = hb[jj];
                float cr[CD] = {ca.x, ca.y, ca.z, ca.w, cb4.x, cb4.y, cb4.z, cb4.w};
#pragma unroll
                for (int q = 0; q < 4; ++q) {
                    float sc0 = -hv;
#pragma unroll
                    for (int k = 0; k < CD; ++k) sc0 = fmaf(cr[k], en4[q][k], sc0);
                    if (sc0 > best[q]) { best[q] = sc0; bidx[q] = jj; }  // strict > : first idx
                }
            }
        }
#pragma unroll
        for (int q = 0; q < 4; ++q) bidx[q] += chunk * 64;

        // wave-internal reduce over the 4 chunks held by lanes l, l+16, l+32, l+48
        // (ascending chunk order + strict > preserves first-index tie-break)
#pragma unroll
        for (int q = 0; q < 4; ++q) {
            float b1 = __shfl_down(best[q], 16, 64);
            int   i1 = __shfl_down(bidx[q], 16, 64);
            if (b1 > best[q]) { best[q] = b1; bidx[q] = i1; }
            float b2 = __shfl_down(best[q], 32, 64);
            int   i2 = __shfl_down(bidx[q], 32, 64);
            if (b2 > best[q]) { best[q] = b2; bidx[q] = i2; }
        }
        if (l < 16) {
#pragma unroll
            for (int q = 0; q < 4; ++q) {
                redS[s * TBLK + 4 * l + q] = best[q];
                redI[s * TBLK + 4 * l + q] = bidx[q];
            }
        }
        __syncthreads();

        // final reduce across 4 waves (ascending wave = ascending entry range)
        float bsc = redS[c];
        int   bi  = redI[c];
#pragma unroll
        for (int ww = 1; ww < 4; ++ww) {
            float v2 = redS[ww * TBLK + c];
            int   vi = redI[ww * TBLK + c];
            if (v2 > bsc) { bsc = v2; bi = vi; }
        }
        if (s == 0) o_codes[(size_t)b * NCB * T + (size_t)i * T + t] = (float)bi;

        // straight-through zq = z_e + (cb_raw[idx] - z_e); loss (once per column)
        float zq[CD];
        {
            float zer[CD];
#pragma unroll
            for (int j = 0; j < CD; ++j) zer[j] = zen[c * 9 + j];
            const float4* cr4 = (const float4*)(codebook + ((size_t)i * CB + bi) * CD);
            float4 qa = cr4[0], qb = cr4[1];
            float cv[CD] = {qa.x, qa.y, qa.z, qa.w, qb.x, qb.y, qb.z, qb.w};
#pragma unroll
            for (int j = 0; j < CD; ++j) {
                zq[j] = zer[j] + (cv[j] - zer[j]);
                if (s == 0) { float dd = cv[j] - zer[j]; loss_local = fmaf(dd, dd, loss_local); }
            }
        }

        // out_proj + residual update: wave owns rows d in [su*32, su*32+32)
        {
            const float* ow = out_w + (size_t)(i * D + su * 32) * CD;  // uniform
            const float* ob = out_b + i * D + su * 32;                 // uniform
#pragma unroll 4
            for (int k = 0; k < 32; ++k) {
                float acc = ob[k];
#pragma unroll
                for (int j = 0; j < CD; ++j) acc = fmaf(ow[k * CD + j], zq[j], acc);
                res[(su * 32 + k) * TBLK + c] -= acc;   // unique owner per (d,c)
            }
        }
    }
    __syncthreads();

    // ---------------- final: z_q = z - residual (recompute z) --------------
    {
        const float* xm = x     + (size_t)b * 2 * D * T + (size_t)(su * 32) * T + t;
        const float* xs = xm    + (size_t)D * T;
        const float* nz = noise + (size_t)b * D * T     + (size_t)(su * 32) * T + t;
        float*       oq = o_zq  + (size_t)b * D * T     + (size_t)(su * 32) * T + t;
#pragma unroll 8
        for (int k = 0; k < 32; ++k) {
            float m  = xm[(size_t)k * T];
            float sc = xs[(size_t)k * T];
            float nv = nz[(size_t)k * T];
            float sp = fmaxf(sc, 0.f) + log1pf(expf(-fabsf(sc)));
            float sd = sp + 1e-4f;
            float zv = fmaf(nv, sd, m);
            oq[(size_t)k * T] = zv - res[(su * 32 + k) * TBLK + c];
        }
    }

    // ---------------- scalar reductions ------------------------------------
    float v = kl_local;
#pragma unroll
    for (int o = 32; o > 0; o >>= 1) v += __shfl_down(v, o, 64);
    float w2 = loss_local;
#pragma unroll
    for (int o = 32; o > 0; o >>= 1) w2 += __shfl_down(w2, o, 64);
    if ((tid & 63) == 0) { redw[s] = v; redw[4 + s] = w2; }
    __syncthreads();
    if (tid == 0) {
        float ks = redw[0] + redw[1] + redw[2] + redw[3];
        float ls = redw[4] + redw[5] + redw[6] + redw[7];
        atomicAdd(&o_scal[0], ks * (1.0f / 65536.0f));               // kl: /(B*T)
        float lsn = ls * (1.0f / (524288.0f * 9.0f));                // /(B*8*T)/NCB
        atomicAdd(&o_scal[1], lsn);                                  // commitment
        atomicAdd(&o_scal[2], lsn);                                  // codebook (identical in eval)
    }
}

extern "C" void kernel_launch(void* const* d_in, const int* in_sizes, int n_in,
                              void* d_out, int out_size, void* d_ws, size_t ws_size,
                              hipStream_t stream) {
    const float* x        = (const float*)d_in[0];
    const float* noise    = (const float*)d_in[1];
    const float* in_w     = (const float*)d_in[2];
    const float* in_b     = (const float*)d_in[3];
    const float* codebook = (const float*)d_in[4];
    const float* out_w    = (const float*)d_in[5];
    const float* out_b    = (const float*)d_in[6];

    float* out     = (float*)d_out;
    float* o_zq    = out + OFF_ZQ;
    float* o_scal  = out + OFF_SCAL;
    float* o_codes = out + OFF_CODES;
    float* o_lat   = out + OFF_LAT;

    // workspace: normalized codebook + half squared norms
    float* cbn = (float*)d_ws;                 // 9*1024*8 floats
    float* h2  = cbn + (size_t)NCB * CB * CD;  // 9*1024 floats

    prep_kernel<<<(NCB * CB + 255) / 256, 256, 0, stream>>>(codebook, cbn, h2, o_scal);

    dim3 grid(BB * (T / TBLK));  // 16 * 64 = 1024 blocks
    rvq_kernel<<<grid, NTHR, 0, stream>>>(x, noise, in_w, in_b, codebook, out_w, out_b,
                                          cbn, h2, o_zq, o_scal, o_codes, o_lat);
}